// Round 8
// baseline (222.447 us; speedup 1.0000x reference)
//
#include <hip/hip_runtime.h>
#include <math.h>

#define H 32
#define S 64
#define K 64
#define B 32
#define NTILE 2048          // B*S
#define GRID 512            // 2 blocks/CU guaranteed -> all co-resident
#define NBIGW (GRID * 4 - 32)   // 2016 big waves

__device__ __forceinline__ float gelu_f(float x) {
    return 0.5f * x * (1.0f + erff(x * 0.70710678118654752440f));
}

// wave-scope LDS ordering (no vmcnt drain)
__device__ __forceinline__ void lds_fence() {
    asm volatile("s_waitcnt lgkmcnt(0)" ::: "memory");
}

__device__ __forceinline__ float bcast_lane(float v, int lane) {
    return __uint_as_float(__builtin_amdgcn_readlane(__float_as_uint(v), lane));
}

// ws layout (floats):
// [0, 2080)              pe (65 x 32)
// [2080, 67616)          energies (32 x 64 x 32)
// [67616, 69664)         partials (2048, indexed by bi = b*64+i)
// [69664, 71712)         flags (2048 ints, indexed by t = i*32+b)
// [71712]                ctr (int)

__global__ void precompute_kernel(float* __restrict__ pe, int* __restrict__ flags,
                                  int* __restrict__ ctr) {
    int t = blockIdx.x * 256 + threadIdx.x;
    if (t == 0) ctr[0] = 0;
    if (t < NTILE) flags[t] = 0;
    if (t < 65 * 32) {
        int p = t >> 5, c = t & 31;
        int iq = c >> 1;
        double dt = pow(10000.0, (double)(2 * iq) / 32.0);
        float ang = (float)p * (float)dt;   // f32 rounding matches reference
        double v = (c & 1) ? cos((double)ang) : sin((double)ang);
        pe[t] = (float)v;
    }
}

__global__ __launch_bounds__(256, 2) void fused_kernel(
    const int* __restrict__ neighbor_ids,
    const int* __restrict__ param_indices,
    const float* __restrict__ weights,
    const float* __restrict__ biases,
    const float* __restrict__ node_bias,
    const float* __restrict__ pe_g,
    const float* __restrict__ positions,
    float* __restrict__ energies,
    float* __restrict__ partials,
    int* __restrict__ flags,
    int* __restrict__ ctr,
    float* __restrict__ out) {
    const int bid = blockIdx.x;
    const int tid = threadIdx.x;
    const int wv = tid >> 6;
    const int lane = tid & 63;
    const int gw = bid * 4 + wv;

    // chain LDS (used only by blocks < 32, wave 0)
    __shared__ int c_idx[S];
    __shared__ float c_pos[S];
    __shared__ float c_pe[(S + 1) * H];
    __shared__ float c_bias[S * H];
    // big LDS
    __shared__ float en_sh[4][K];
    // reduce LDS
    __shared__ float red_sh[256];

    if (bid < 32 && wv == 0) {
        // ================= CHAIN (one wave, b = bid) =================
        const int b = bid;
        const int l = lane;
        const int r = l >> 5;
        const int d = l & 31;

        c_idx[l] = param_indices[((size_t)(b * S + l)) * K];
        c_pos[l] = positions[l];
        for (int t = l; t < (S + 1) * H; t += 64) c_pe[t] = pe_g[t];
        lds_fence();

        for (int t = l; t < S * H; t += 64)
            c_bias[t] = biases[(size_t)c_idx[t >> 5] * H + (t & 31)];

        float w0[16], w1[16], w2[16], w3[16];
        const int rowoff = r * 16;
        auto loadW = [&](float (&wb)[16], int step) {
            const float* Wp = weights + (size_t)c_idx[step] * (H * H) + (size_t)rowoff * H + d;
            #pragma unroll
            for (int j = 0; j < 16; ++j) wb[j] = Wp[j * H];
        };
        loadW(w0, 0); loadW(w1, 1); loadW(w2, 2); loadW(w3, 3);

        float init_e;
        {
            int nid = neighbor_ids[(size_t)b * S * K * 2];  // [b,0,0,0]
            init_e = gelu_f(0.03125f + node_bias[(size_t)nid * H + d] + c_pe[d]);
        }
        lds_fence();

        float m = -1e30f, ssum = 0.0f, A = 0.0f, nxtprev = 0.0f;

        auto step = [&](float (&wb)[16], int i) {
            float e;
            if (i == 0) {
                e = init_e;
            } else {
                float p = c_pos[i - 1];
                if (p > m) { float sc = expf(m - p); A *= sc; ssum *= sc; m = p; }
                float wgt = expf(p - m);
                A = fmaf(wgt, nxtprev, A);
                ssum += wgt;
                e = A / ssum;
            }
            // publish e for big waves: write-through (sc1) store + release flag
            if (r == 0)
                __hip_atomic_store(&energies[((size_t)(b * S + i)) * H + d], e,
                                   __ATOMIC_RELAXED, __HIP_MEMORY_SCOPE_AGENT);
            if (l == 0)
                __hip_atomic_store(&flags[i * 32 + b], 1,
                                   __ATOMIC_RELEASE, __HIP_MEMORY_SCOPE_AGENT);
            if (i + 4 < S) loadW(wb, i + 4);   // refill after the release drain

            float a0 = 0.0f, a1 = 0.0f, a2 = 0.0f, a3 = 0.0f;  // 4-way FMA tree
            #pragma unroll
            for (int j = 0; j < 4; ++j) {
                float e0, e1;
                e0 = bcast_lane(e, 4 * j + 0); e1 = bcast_lane(e, 16 + 4 * j + 0);
                a0 = fmaf(r ? e1 : e0, wb[4 * j + 0], a0);
                e0 = bcast_lane(e, 4 * j + 1); e1 = bcast_lane(e, 16 + 4 * j + 1);
                a1 = fmaf(r ? e1 : e0, wb[4 * j + 1], a1);
                e0 = bcast_lane(e, 4 * j + 2); e1 = bcast_lane(e, 16 + 4 * j + 2);
                a2 = fmaf(r ? e1 : e0, wb[4 * j + 2], a2);
                e0 = bcast_lane(e, 4 * j + 3); e1 = bcast_lane(e, 16 + 4 * j + 3);
                a3 = fmaf(r ? e1 : e0, wb[4 * j + 3], a3);
            }
            float acc = (a0 + a1) + (a2 + a3);
            acc += __shfl_xor(acc, 32, 64);
            nxtprev = gelu_f(acc + c_bias[i * H + d] + c_pe[(i + 1) * H + d]);
        };

        #pragma unroll
        for (int ii = 0; ii < S; ii += 4) {
            step(w0, ii); step(w1, ii + 1); step(w2, ii + 2); step(w3, ii + 3);
        }
    } else {
        // ================= BIG (one wave per tile) =================
        int bigrank = gw - min((gw + 3) >> 2, 32);
        const int q = lane >> 4;
        const int dp = lane & 15;

        for (int t = bigrank; t < NTILE; t += NBIGW) {
            const int b = t & 31, i = t >> 5;
            const int bi = b * S + i;

            // wait for chain to publish energies(b,i) — relaxed spin, no cache ops
            if (__hip_atomic_load(&flags[t], __ATOMIC_RELAXED, __HIP_MEMORY_SCOPE_AGENT) == 0) {
                do { __builtin_amdgcn_s_sleep(2); }
                while (__hip_atomic_load(&flags[t], __ATOMIC_RELAXED, __HIP_MEMORY_SCOPE_AGENT) == 0);
            }

            float pex = pe_g[(i + 1) * H + 2 * dp];
            float pey = pe_g[(i + 1) * H + 2 * dp + 1];
            int idxv = param_indices[(size_t)bi * K + lane];   // lane l holds idx[l]
            float ereg[8];
            #pragma unroll
            for (int hh = 0; hh < 8; ++hh)
                ereg[hh] = __hip_atomic_load(&energies[(size_t)bi * H + hh * 4 + q],
                                             __ATOMIC_RELAXED, __HIP_MEMORY_SCOPE_AGENT);

            int ia = __builtin_amdgcn_readlane(idxv, 0);
            int ib = __builtin_amdgcn_readlane(idxv, 32);
            float2 ca[8], cb[8], bca, bcb;
            {
                const float2* Wa = (const float2*)(weights + (size_t)ia * (H * H));
                const float2* Wb = (const float2*)(weights + (size_t)ib * (H * H));
                #pragma unroll
                for (int hh = 0; hh < 8; ++hh) {
                    ca[hh] = Wa[(hh * 4 + q) * 16 + dp];
                    cb[hh] = Wb[(hh * 4 + q) * 16 + dp];
                }
                bca = *(const float2*)(biases + (size_t)ia * H + 2 * dp);
                bcb = *(const float2*)(biases + (size_t)ib * H + 2 * dp);
            }

            for (int it = 0; it < 32; ++it) {
                float2 na[8], nb[8], bna, bnb;
                if (it < 31) {
                    int ja = __builtin_amdgcn_readlane(idxv, it + 1);
                    int jb = __builtin_amdgcn_readlane(idxv, it + 33);
                    const float2* Wa = (const float2*)(weights + (size_t)ja * (H * H));
                    const float2* Wb = (const float2*)(weights + (size_t)jb * (H * H));
                    #pragma unroll
                    for (int hh = 0; hh < 8; ++hh) {
                        na[hh] = Wa[(hh * 4 + q) * 16 + dp];
                        nb[hh] = Wb[(hh * 4 + q) * 16 + dp];
                    }
                    bna = *(const float2*)(biases + (size_t)ja * H + 2 * dp);
                    bnb = *(const float2*)(biases + (size_t)jb * H + 2 * dp);
                }

                float axa = 0, aya = 0, axb = 0, ayb = 0;
                #pragma unroll
                for (int hh = 0; hh < 8; ++hh) {
                    axa = fmaf(ereg[hh], ca[hh].x, axa);
                    aya = fmaf(ereg[hh], ca[hh].y, aya);
                    axb = fmaf(ereg[hh], cb[hh].x, axb);
                    ayb = fmaf(ereg[hh], cb[hh].y, ayb);
                }
                axa += __shfl_xor(axa, 16, 64); aya += __shfl_xor(aya, 16, 64);
                axb += __shfl_xor(axb, 16, 64); ayb += __shfl_xor(ayb, 16, 64);
                axa += __shfl_xor(axa, 32, 64); aya += __shfl_xor(aya, 32, 64);
                axb += __shfl_xor(axb, 32, 64); ayb += __shfl_xor(ayb, 32, 64);
                float v0a = gelu_f(axa + bca.x + pex);
                float v1a = gelu_f(aya + bca.y + pey);
                float v0b = gelu_f(axb + bcb.x + pex);
                float v1b = gelu_f(ayb + bcb.y + pey);
                float ssa = fmaf(v0a, v0a, v1a * v1a);
                float ssb = fmaf(v0b, v0b, v1b * v1b);
                #pragma unroll
                for (int mk = 8; mk; mk >>= 1) {
                    ssa += __shfl_xor(ssa, mk, 64);
                    ssb += __shfl_xor(ssb, mk, 64);
                }
                if (lane == 0) {
                    en_sh[wv][it]      = sqrtf(ssa);
                    en_sh[wv][it + 32] = sqrtf(ssb);
                }
                if (it < 31) {
                    #pragma unroll
                    for (int hh = 0; hh < 8; ++hh) { ca[hh] = na[hh]; cb[hh] = nb[hh]; }
                    bca = bna; bcb = bnb;
                }
            }
            lds_fence();
            float en = en_sh[wv][lane];
            float mm = en;
            #pragma unroll
            for (int mk = 32; mk; mk >>= 1) mm = fmaxf(mm, __shfl_xor(mm, mk, 64));
            float sx = expf(en - mm);
            #pragma unroll
            for (int mk = 32; mk; mk >>= 1) sx += __shfl_xor(sx, mk, 64);
            float en0 = bcast_lane(en, 0);
            if (lane == 0)
                __hip_atomic_store(&partials[bi], mm + logf(sx) - en0,
                                   __ATOMIC_RELAXED, __HIP_MEMORY_SCOPE_AGENT);
        }
    }

    // ---- deterministic finalization ----
    __syncthreads();
    if (tid == 0)
        __hip_atomic_fetch_add(ctr, 1, __ATOMIC_RELEASE, __HIP_MEMORY_SCOPE_AGENT);
    if (bid == 0) {
        if (tid == 0) {
            while (__hip_atomic_load(ctr, __ATOMIC_RELAXED, __HIP_MEMORY_SCOPE_AGENT) < GRID)
                __builtin_amdgcn_s_sleep(8);
        }
        __syncthreads();
        float s = 0.0f;
        for (int j = 0; j < 8; ++j)
            s += __hip_atomic_load(&partials[tid + j * 256],
                                   __ATOMIC_RELAXED, __HIP_MEMORY_SCOPE_AGENT);
        red_sh[tid] = s;
        __syncthreads();
        for (int ofs = 128; ofs; ofs >>= 1) {
            if (tid < ofs) red_sh[tid] += red_sh[tid + ofs];
            __syncthreads();
        }
        if (tid == 0) out[0] = red_sh[0] * (1.0f / 2048.0f);
    }
}

extern "C" void kernel_launch(void* const* d_in, const int* in_sizes, int n_in,
                              void* d_out, int out_size, void* d_ws, size_t ws_size,
                              hipStream_t stream) {
    const int*   neighbor_ids  = (const int*)d_in[0];
    const int*   param_indices = (const int*)d_in[1];
    const float* weights       = (const float*)d_in[2];
    const float* biases        = (const float*)d_in[3];
    const float* node_bias     = (const float*)d_in[4];
    const float* positions     = (const float*)d_in[5];

    float* ws       = (float*)d_ws;
    float* pe       = ws;                    // 2080
    float* energies = ws + 2080;             // 65536
    float* partials = ws + 2080 + B * S * H; // 2048
    int*   flags    = (int*)(ws + 69664);    // 2048
    int*   ctr      = (int*)(ws + 71712);    // 1

    hipLaunchKernelGGL(precompute_kernel, dim3(9), dim3(256), 0, stream,
                       pe, flags, ctr);
    hipLaunchKernelGGL(fused_kernel, dim3(GRID), dim3(256), 0, stream,
                       neighbor_ids, param_indices, weights, biases, node_bias,
                       pe, positions, energies, partials, flags, ctr,
                       (float*)d_out);
}

// Round 9
// 140.055 us; speedup vs baseline: 1.5883x; 1.5883x over previous
//
#include <hip/hip_runtime.h>
#include <math.h>

#define H 32
#define S 64
#define K 64
#define B 32

__device__ __forceinline__ float gelu_f(float x) {
    return 0.5f * x * (1.0f + erff(x * 0.70710678118654752440f));
}

// Single-wave LDS ordering fence: waits LDS ops WITHOUT draining vmcnt.
__device__ __forceinline__ void lds_fence() {
    asm volatile("s_waitcnt lgkmcnt(0)" ::: "memory");
}

__device__ __forceinline__ float bcast_lane(float v, int lane) {
    return __uint_as_float(__builtin_amdgcn_readlane(__float_as_uint(v), lane));
}

// ws layout (floats):
// [0, 2080)              pe (65 x 32)
// [2080, 67616)          energies (32 x 64 x 32)
// [67616, 69664)         partials (2048)

__global__ void precompute_kernel(float* __restrict__ pe) {
    int t = blockIdx.x * 256 + threadIdx.x;
    if (t < 65 * 32) {
        int p = t >> 5, c = t & 31;
        int iq = c >> 1;
        double dt = pow(10000.0, (double)(2 * iq) / 32.0);
        float ang = (float)p * (float)dt;   // f32 rounding matches reference
        double v = (c & 1) ? cos((double)ang) : sin((double)ang);
        pe[t] = (float)v;
    }
}

// One single-wave block per batch row b. ALL-REGISTER step loop (R7 verbatim:
// sequential fmaf chain -> absmax 0).
__global__ __launch_bounds__(64) void chain_kernel(
    const int* __restrict__ neighbor_ids,
    const int* __restrict__ param_indices,
    const float* __restrict__ weights,
    const float* __restrict__ biases,
    const float* __restrict__ node_bias,
    const float* __restrict__ pe_g,
    const float* __restrict__ positions,
    float* __restrict__ energies) {
    int b = blockIdx.x;
    int l = threadIdx.x;      // 0..63
    int r = l >> 5;           // row-phase 0/1 (h-halves)
    int d = l & 31;           // output column

    __shared__ int idx_sh[S];
    __shared__ float pos_sh[S];
    __shared__ float pe_sh[(S + 1) * H];
    __shared__ float bias_sh[S * H];

    idx_sh[l] = param_indices[((size_t)(b * S + l)) * K];   // k=0 index per step
    pos_sh[l] = positions[l];
    for (int t = l; t < (S + 1) * H; t += 64) pe_sh[t] = pe_g[t];
    lds_fence();   // idx/pos/pe visible

    for (int t = l; t < S * H; t += 64)
        bias_sh[t] = biases[(size_t)idx_sh[t >> 5] * H + (t & 31)];

    float init_e;
    {
        int nid = neighbor_ids[(size_t)b * S * K * 2];  // [b,0,0,0]
        init_e = gelu_f(0.03125f + node_bias[(size_t)nid * H + d] + pe_sh[d]);
    }
    lds_fence();   // bias_sh visible

    float w0[16], w1[16], w2[16], w3[16];
    const int rowoff = r * 16;

    auto loadW = [&](float (&wb)[16], int step) {
        const float* Wp = weights + (size_t)idx_sh[step] * (H * H) + (size_t)rowoff * H + d;
        #pragma unroll
        for (int j = 0; j < 16; ++j) wb[j] = Wp[j * H];
    };
    loadW(w0, 0); loadW(w1, 1); loadW(w2, 2); loadW(w3, 3);

    float m = -1e30f, ssum = 0.0f, A = 0.0f, nxtprev = 0.0f;

    auto step = [&](float (&wb)[16], int i) {
        float e;
        if (i == 0) {
            e = init_e;
        } else {
            float p = pos_sh[i - 1];
            if (p > m) { float sc = expf(m - p); A *= sc; ssum *= sc; m = p; }
            float wgt = expf(p - m);
            A = fmaf(wgt, nxtprev, A);
            ssum += wgt;
            e = A / ssum;
        }
        if (r == 0) energies[((size_t)(b * S + i)) * H + d] = e;

        float acc = 0.0f;
        #pragma unroll
        for (int j = 0; j < 16; ++j) {
            float e0 = bcast_lane(e, j);
            float e1 = bcast_lane(e, 16 + j);
            acc = fmaf(r ? e1 : e0, wb[j], acc);
        }
        acc += __shfl_xor(acc, 32, 64);
        nxtprev = gelu_f(acc + bias_sh[i * H + d] + pe_sh[(i + 1) * H + d]);
        if (i + 4 < S) loadW(wb, i + 4);
    };

    #pragma unroll
    for (int ii = 0; ii < S; ii += 4) {
        step(w0, ii);
        step(w1, ii + 1);
        step(w2, ii + 2);
        step(w3, ii + 3);
    }
}

// One block (256 thr, 4 waves) per (b,i). LDS-staged gather:
// each wave streams its 16 matrices through a private 2-slot LDS ring via
// global_load_lds (16B wide), counted s_waitcnt vmcnt(4) (never 0), with an
// XOR-swizzled source + swizzled ds_read so column reads are conflict-free.
__global__ __launch_bounds__(256) void big_kernel(
    const int* __restrict__ param_indices,
    const float* __restrict__ weights,
    const float* __restrict__ biases,
    const float* __restrict__ pe_g,
    const float* __restrict__ energies,
    float* __restrict__ partials) {
    int bi = blockIdx.x;               // b*S + i
    int i = bi & 63;
    int tid = threadIdx.x;
    int wv = tid >> 6;                 // 0..3
    int lane = tid & 63;
    int q = lane >> 4;                 // row-phase 0..3
    int dp = lane & 15;                // column-pair

    __shared__ float wslab[4][2][1024];   // 4 waves x 2 slots x 4KB
    __shared__ float bias_sh[K * H];      // 8KB: bias rows for all 64 matrices
    __shared__ float e_sh[H];
    __shared__ float en_sh[K];
    __shared__ int idx_sh[K];

    if (tid < H) e_sh[tid] = energies[(size_t)bi * H + tid];
    if (tid < K) idx_sh[tid] = param_indices[(size_t)bi * K + tid];
    __syncthreads();

    // stage all 64 bias rows: thread t covers matrix t>>2, 8 floats
    {
        int k = tid >> 2, part = tid & 3;
        const float4* bp = (const float4*)(biases + (size_t)idx_sh[k] * H + part * 8);
        float4 b0 = bp[0], b1 = bp[1];
        ((float4*)&bias_sh[k * H + part * 8])[0] = b0;
        ((float4*)&bias_sh[k * H + part * 8])[1] = b1;
    }
    float pex = pe_g[(i + 1) * H + 2 * dp];
    float pey = pe_g[(i + 1) * H + 2 * dp + 1];
    __syncthreads();   // drains vmcnt -> clean counter for the staging pipeline

    float ereg[8];
    #pragma unroll
    for (int hh = 0; hh < 8; ++hh) ereg[hh] = e_sh[hh * 4 + q];

    // swizzled per-lane source granule: involution p ^= ((p>>7)&3)<<5
    const int lsw = lane ^ (((lane >> 3) & 3) << 1);

    auto stage = [&](int m, int slot) {
        int idx = idx_sh[wv * 16 + m];
        const char* src = (const char*)(weights + (size_t)idx * (H * H)) + lsw * 16;
        char* dst = (char*)&wslab[wv][slot][0];
        #pragma unroll
        for (int j = 0; j < 4; ++j) {
            __builtin_amdgcn_global_load_lds(
                (const __attribute__((address_space(1))) void*)(src + j * 1024),
                (__attribute__((address_space(3))) void*)(dst + j * 1024),
                16, 0, 0);
        }
    };

    stage(0, 0);

    #pragma unroll
    for (int m = 0; m < 16; ++m) {
        const int slot = m & 1;
        if (m + 1 < 16) {
            stage(m + 1, (m + 1) & 1);
            asm volatile("s_waitcnt vmcnt(4)" ::: "memory");   // slot m complete, next stays in flight
        } else {
            asm volatile("s_waitcnt vmcnt(0)" ::: "memory");
        }
        __builtin_amdgcn_sched_barrier(0);

        const char* Wl = (const char*)&wslab[wv][slot][0];
        float ax = 0.0f, ay = 0.0f;
        #pragma unroll
        for (int hh = 0; hh < 8; ++hh) {
            float2 w = *(const float2*)(Wl + hh * 512 + q * 128 + ((dp * 8) ^ (q << 5)));
            ax = fmaf(ereg[hh], w.x, ax);
            ay = fmaf(ereg[hh], w.y, ay);
        }
        ax += __shfl_xor(ax, 16, 64); ay += __shfl_xor(ay, 16, 64);
        ax += __shfl_xor(ax, 32, 64); ay += __shfl_xor(ay, 32, 64);

        const int k = wv * 16 + m;
        float2 bv = *(const float2*)&bias_sh[k * H + 2 * dp];
        float v0 = gelu_f(ax + bv.x + pex);
        float v1 = gelu_f(ay + bv.y + pey);
        float ss = fmaf(v0, v0, v1 * v1);
        #pragma unroll
        for (int mk = 8; mk; mk >>= 1) ss += __shfl_xor(ss, mk, 64);
        if (lane == 0) en_sh[k] = sqrtf(ss);
    }
    __syncthreads();

    // logsumexp over the 64 norms (wave 0 only)
    if (tid < K) {
        float en = en_sh[tid];
        float mm = en;
        #pragma unroll
        for (int mk = 32; mk; mk >>= 1) mm = fmaxf(mm, __shfl_xor(mm, mk, 64));
        float s = expf(en - mm);
        #pragma unroll
        for (int mk = 32; mk; mk >>= 1) s += __shfl_xor(s, mk, 64);
        if (tid == 0) partials[bi] = mm + logf(s) - en_sh[0];
    }
}

// Deterministic fixed-order reduction of the 2048 partials.
__global__ __launch_bounds__(256) void reduce_kernel(const float* __restrict__ partials,
                                                     float* __restrict__ out) {
    __shared__ float sh[256];
    int tid = threadIdx.x;
    float s = 0.0f;
    for (int j = 0; j < 8; ++j) s += partials[tid + j * 256];
    sh[tid] = s;
    __syncthreads();
    for (int ofs = 128; ofs; ofs >>= 1) {
        if (tid < ofs) sh[tid] += sh[tid + ofs];
        __syncthreads();
    }
    if (tid == 0) out[0] = sh[0] * (1.0f / 2048.0f);
}

extern "C" void kernel_launch(void* const* d_in, const int* in_sizes, int n_in,
                              void* d_out, int out_size, void* d_ws, size_t ws_size,
                              hipStream_t stream) {
    const int*   neighbor_ids  = (const int*)d_in[0];
    const int*   param_indices = (const int*)d_in[1];
    const float* weights       = (const float*)d_in[2];
    const float* biases        = (const float*)d_in[3];
    const float* node_bias     = (const float*)d_in[4];
    const float* positions     = (const float*)d_in[5];

    float* ws       = (float*)d_ws;
    float* pe       = ws;                    // 2080
    float* energies = ws + 2080;             // 65536
    float* partials = ws + 2080 + B * S * H; // 2048

    hipLaunchKernelGGL(precompute_kernel, dim3(9), dim3(256), 0, stream, pe);
    hipLaunchKernelGGL(chain_kernel, dim3(B), dim3(64), 0, stream,
                       neighbor_ids, param_indices, weights, biases, node_bias,
                       pe, positions, energies);
    hipLaunchKernelGGL(big_kernel, dim3(B * S), dim3(256), 0, stream,
                       param_indices, weights, biases, pe, energies, partials);
    hipLaunchKernelGGL(reduce_kernel, dim3(1), dim3(256), 0, stream,
                       partials, (float*)d_out);
}